// Round 1
// baseline (301.060 us; speedup 1.0000x reference)
//
#include <hip/hip_runtime.h>

// x: (B=64, GS=96, C=8, C=8) float32
// out[b,i,j,c1,c2,k] : (B, 96, 96, 8, 8, 2) float32
//   k=0 -> x[b,i,c1,c2]   k=1 -> x[b,j,c1,c2]
// Pure broadcast: 1.5 MB read, 302 MB write -> write-BW bound (~48 us floor).

constexpr int GS = 96;
constexpr int CC = 64;           // C*C floats per (b,g) tile
constexpr int F4_PER_J = 32;     // 8*8*2 floats / 4 per (b,i,j) tile
constexpr int F4_PER_SLAB = GS * F4_PER_J;  // 3072 float4 per (b,i) slab

__global__ __launch_bounds__(256)
void gcom_combo_kernel(const float* __restrict__ x, float4* __restrict__ out) {
    const int i = blockIdx.x;    // 0..GS-1
    const int b = blockIdx.y;    // 0..B-1

    __shared__ float shB[GS * CC];   // whole x[b] slice: 24 KB

    // cooperative stage: 96*64 floats = 1536 float4, 6 per thread
    const float4* xb4 = (const float4*)(x + (size_t)b * (GS * CC));
    float4* sh4 = (float4*)shB;
    #pragma unroll
    for (int t = threadIdx.x; t < GS * CC / 4; t += 256) {
        sh4[t] = xb4[t];
    }
    __syncthreads();

    const float* A = shB + i * CC;   // row i fragment
    float4* outSlab = out + (size_t)(b * GS + i) * F4_PER_SLAB;

    #pragma unroll
    for (int it = 0; it < F4_PER_SLAB / 256; ++it) {   // 12 iterations
        const int f  = threadIdx.x + it * 256;  // 0..3071
        const int j  = f >> 5;                  // which partner row
        const int q  = f & 31;                  // position within (i,j) tile
        const int c1 = q >> 2;
        const int p  = q & 3;                   // c2 pair index

        const int off = c1 * 8 + 2 * p;
        const float a0 = A[off];
        const float a1 = A[off + 1];
        const float* Bj = shB + j * CC + off;
        const float b0 = Bj[0];
        const float b1 = Bj[1];

        // elements: (c1,2p,k=0)=xi, (c1,2p,k=1)=xj, (c1,2p+1,0)=xi, (c1,2p+1,1)=xj
        outSlab[f] = make_float4(a0, b0, a1, b1);
    }
}

extern "C" void kernel_launch(void* const* d_in, const int* in_sizes, int n_in,
                              void* d_out, int out_size, void* d_ws, size_t ws_size,
                              hipStream_t stream) {
    const float* x = (const float*)d_in[0];
    float4* out = (float4*)d_out;
    const int B = in_sizes[0] / (GS * CC);   // 64
    dim3 grid(GS, B);
    gcom_combo_kernel<<<grid, dim3(256), 0, stream>>>(x, out);
}

// Round 3
// 290.429 us; speedup vs baseline: 1.0366x; 1.0366x over previous
//
#include <hip/hip_runtime.h>

// x: (B=64, GS=96, C=8, C=8) float32
// out[b,i,j,c1,c2,k] : (B, 96, 96, 8, 8, 2) float32
//   k=0 -> x[b,i,c1,c2]   k=1 -> x[b,j,c1,c2]
// Pure broadcast: 1.5 MB read (L2-resident), 302 MB write -> write-BW bound
// (~48 us floor at 6.3 TB/s). Strategy: look like fillBuffer — no LDS, no
// __syncthreads, fixed per-thread values in registers, 12 independent
// load->nontemporal-store pairs per thread, max occupancy.

typedef float f32x4 __attribute__((ext_vector_type(4)));

constexpr int GS = 96;
constexpr int CC = 64;            // C*C floats per (b,g) tile
constexpr int F4_PER_J = 32;      // 8*8*2 floats / 4 per (b,i,j) tile
constexpr int F4_PER_SLAB = GS * F4_PER_J;  // 3072 float4 per (b,i) slab

__global__ __launch_bounds__(256)
void gcom_combo_kernel(const float* __restrict__ x, f32x4* __restrict__ out) {
    const int i = blockIdx.x;     // 0..GS-1
    const int b = blockIdx.y;     // 0..B-1
    const int t = threadIdx.x;

    // Fixed per-thread position within each (i,j) 32-float4 tile:
    const int q  = t & 31;        // 0..31
    const int jb = t >> 5;        // 0..7 : base j
    const int c1 = q >> 2;
    const int p  = q & 3;
    const int off = c1 * 8 + 2 * p;

    const float* xb = x + (size_t)b * (GS * CC);
    // A-row pair (k=0 values) — loop-invariant, held in registers.
    const float2 a = *(const float2*)(xb + i * CC + off);

    f32x4* outSlab = out + (size_t)(b * GS + i) * F4_PER_SLAB;

    #pragma unroll
    for (int it = 0; it < 12; ++it) {
        const int j = jb + it * 8;
        const float2 bv = *(const float2*)(xb + j * CC + off);
        // f32x4 covers (c2=2p,k=0),(2p,k=1),(2p+1,k=0),(2p+1,k=1)
        f32x4 v = { a.x, bv.x, a.y, bv.y };
        // f = j*32 + q = t + it*256 -> lanes contiguous, 1KB/wave stores
        __builtin_nontemporal_store(v, &outSlab[j * F4_PER_J + q]);
    }
}

extern "C" void kernel_launch(void* const* d_in, const int* in_sizes, int n_in,
                              void* d_out, int out_size, void* d_ws, size_t ws_size,
                              hipStream_t stream) {
    const float* x = (const float*)d_in[0];
    f32x4* out = (f32x4*)d_out;
    const int B = in_sizes[0] / (GS * CC);   // 64
    dim3 grid(GS, B);
    gcom_combo_kernel<<<grid, dim3(256), 0, stream>>>(x, out);
}